// Round 6
// baseline (876.768 us; speedup 1.0000x reference)
//
#include <hip/hip_runtime.h>
#include <hip/hip_bf16.h>
#include <math.h>

// Problem constants (fixed by the reference file)
#define NPTS 262144
#define NP   128
#define DD   64
#define NWORDS (NPTS / 64)   // 4096 u64 ballot words per plane

// ---------------------------------------------------------------------------
// Prep: pack plane params to [P][12] floats (normal.xyz+offs | min.xyz | max.xyz)
// -> fused kernel reads them wave-uniformly (s_load, SMEM pipe, no LDS/barrier).
// Also zero out_feats (16384 floats) for the atomic-max pool.
// ---------------------------------------------------------------------------
__global__ __launch_bounds__(256) void prep_kernel(
    const float* __restrict__ plane_center, const float* __restrict__ plane_normal,
    const float* __restrict__ pmin, const float* __restrict__ pmax,
    float* __restrict__ packed, float* __restrict__ out_feats)
{
    const int t = threadIdx.x;
    out_feats[blockIdx.x * 256 + t] = 0.0f;          // grid = 64 blocks
    if (blockIdx.x == 0 && t < NP) {
        float n0 = plane_normal[t*3+0], n1 = plane_normal[t*3+1], n2 = plane_normal[t*3+2];
        float c0 = plane_center[t*3+0], c1 = plane_center[t*3+1], c2 = plane_center[t*3+2];
        float off = (c0*n0 + c1*n1) + c2*n2;          // matches jnp.sum order
        float4* pp = reinterpret_cast<float4*>(packed) + t * 3;
        pp[0] = make_float4(n0, n1, n2, off);
        pp[1] = make_float4(pmin[t*3+0], pmin[t*3+1], pmin[t*3+2], 0.0f);
        pp[2] = make_float4(pmax[t*3+0], pmax[t*3+1], pmax[t*3+2], 0.0f);
    }
}

// ---------------------------------------------------------------------------
// Fused per-point kernel, round-6 JAMMED structure.
// R4/R5 evidence: fc phase (VALU-only) and mask phase (store-only) are
// additive — each leaves the other pipe idle, and all 1024 blocks are
// co-resident so there is no cross-block stagger. Fix: geometric mask (mk)
// doesn't depend on score, so:
//   Phase A: 32 rolled fc1 q-iters, each jammed with 4 plane-mask iters
//            (compute mk, nontemporal-store out_mask, keep bit in a u64 pair)
//            -> 128 MB stores + 131 MB reads hide under fc1's ~35 us of FMA.
//   Phase B: fc2 (two 32-wide halves, regs <=128) + BN2 + fc3 + h2 store.
//   Phase C: replay mk bits from registers: sm/on/off stores + ballots.
//            Pure store stream, no geometry recompute, no param reloads.
// Same arithmetic/order as round 5 -> bit-identical outputs (absmax 3e-8).
// K-loops rolled (#pragma unroll 1): 32 KB I$ (round-1 lesson).
// ---------------------------------------------------------------------------
__global__ __launch_bounds__(256, 4) void fused_kernel(
    const float* __restrict__ feature, const float* __restrict__ feature_geo,
    const float* __restrict__ xyz, const float* __restrict__ centers,
    const float* __restrict__ packed,
    const float* __restrict__ w1, const float* __restrict__ b1,
    const float* __restrict__ g1, const float* __restrict__ be1,
    const float* __restrict__ m1, const float* __restrict__ v1,
    const float* __restrict__ w2, const float* __restrict__ b2,
    const float* __restrict__ g2, const float* __restrict__ be2,
    const float* __restrict__ m2, const float* __restrict__ v2,
    const float* __restrict__ w3, const float* __restrict__ b3,
    float* __restrict__ h2_out,
    float* __restrict__ out_sm, float* __restrict__ out_mask,
    float* __restrict__ out_on, float* __restrict__ out_off,
    unsigned long long* __restrict__ hitOn, unsigned long long* __restrict__ hitOff)
{
    const int t = threadIdx.x;
    const int n = blockIdx.x * 256 + t;
    const int lane = t & 63;
    const int word = n >> 6;

    // cloud coords needed by the jammed mask iters
    const float c0 = xyz[n*3+0] + centers[0];
    const float c1 = xyz[n*3+1] + centers[1];
    const float c2 = xyz[n*3+2] + centers[2];

    const float4* pp = reinterpret_cast<const float4*>(packed);
    unsigned long long mklo = 0ull, mkhi = 0ull;

    float acc[DD];
#pragma unroll
    for (int j = 0; j < DD; ++j) acc[j] = 0.0f;

    // ---- Phase A part 1: fc1 x feature, jammed with planes 0..63 ----
    const float4* fA = reinterpret_cast<const float4*>(feature) + (size_t)n * 16;
    const float4* fB = reinterpret_cast<const float4*>(feature_geo) + (size_t)n * 16;
#pragma unroll 1
    for (int q = 0; q < 16; ++q) {
        const float4 fv = fA[q];
        const float* wr = w1 + q * 4 * DD;
#pragma unroll
        for (int j = 0; j < DD; ++j) acc[j] = fmaf(fv.x, wr[j], acc[j]);
#pragma unroll
        for (int j = 0; j < DD; ++j) acc[j] = fmaf(fv.y, wr[DD + j], acc[j]);
#pragma unroll
        for (int j = 0; j < DD; ++j) acc[j] = fmaf(fv.z, wr[2 * DD + j], acc[j]);
#pragma unroll
        for (int j = 0; j < DD; ++j) acc[j] = fmaf(fv.w, wr[3 * DD + j], acc[j]);
        // 4 jammed mask iterations (independent of the FMA stream above;
        // VMEM/SALU issue in VALU dead slots)
#pragma unroll
        for (int u = 0; u < 4; ++u) {
            const int p = q * 4 + u;
            const float4 nrm = pp[p*3+0];
            const float4 mn  = pp[p*3+1];
            const float4 mx  = pp[p*3+2];
            float d = fabsf(fmaf(c2, nrm.z, fmaf(c1, nrm.y, c0 * nrm.x)) - nrm.w);
            bool ok0 = (mx.x == 0.0f) | ((c0 >= mn.x) & (c0 < mx.x));
            bool ok1 = (mx.y == 0.0f) | ((c1 >= mn.y) & (c1 < mx.y));
            bool ok2 = (mx.z == 0.0f) | ((c2 >= mn.z) & (c2 < mx.z));
            bool mk  = ok0 & ok1 & ok2 & (d < 0.1f);
            __builtin_nontemporal_store(mk ? 1.0f : 0.0f, &out_mask[(size_t)p * NPTS + n]);
            mklo |= ((unsigned long long)mk) << p;
        }
    }
    // ---- Phase A part 2: fc1 x feature_geo, jammed with planes 64..127 ----
    const float* w1b = w1 + DD * DD;
#pragma unroll 1
    for (int q = 0; q < 16; ++q) {
        const float4 fv = fB[q];
        const float* wr = w1b + q * 4 * DD;
#pragma unroll
        for (int j = 0; j < DD; ++j) acc[j] = fmaf(fv.x, wr[j], acc[j]);
#pragma unroll
        for (int j = 0; j < DD; ++j) acc[j] = fmaf(fv.y, wr[DD + j], acc[j]);
#pragma unroll
        for (int j = 0; j < DD; ++j) acc[j] = fmaf(fv.z, wr[2 * DD + j], acc[j]);
#pragma unroll
        for (int j = 0; j < DD; ++j) acc[j] = fmaf(fv.w, wr[3 * DD + j], acc[j]);
#pragma unroll
        for (int u = 0; u < 4; ++u) {
            const int p = 64 + q * 4 + u;
            const float4 nrm = pp[p*3+0];
            const float4 mn  = pp[p*3+1];
            const float4 mx  = pp[p*3+2];
            float d = fabsf(fmaf(c2, nrm.z, fmaf(c1, nrm.y, c0 * nrm.x)) - nrm.w);
            bool ok0 = (mx.x == 0.0f) | ((c0 >= mn.x) & (c0 < mx.x));
            bool ok1 = (mx.y == 0.0f) | ((c1 >= mn.y) & (c1 < mx.y));
            bool ok2 = (mx.z == 0.0f) | ((c2 >= mn.z) & (c2 < mx.z));
            bool mk  = ok0 & ok1 & ok2 & (d < 0.1f);
            __builtin_nontemporal_store(mk ? 1.0f : 0.0f, &out_mask[(size_t)p * NPTS + n]);
            mkhi |= ((unsigned long long)mk) << (p - 64);
        }
    }
    // BN1 + ReLU -> h1
    float h1[DD];
#pragma unroll
    for (int j = 0; j < DD; ++j) {
        float sc = g1[j] * (1.0f / sqrtf(v1[j] + 1e-5f));
        float h  = fmaf(acc[j] + b1[j] - m1[j], sc, be1[j]);
        h1[j] = fmaxf(h, 0.0f);
    }

    // ---- Phase B: fc2 + BN2 + ReLU + fc3 + h2 store (two 32-wide halves) ----
    float s = 0.0f;
    float4* o = reinterpret_cast<float4*>(h2_out) + (size_t)n * 16;
#pragma unroll 1
    for (int hh = 0; hh < 2; ++hh) {
        float a2[32];
#pragma unroll
        for (int j = 0; j < 32; ++j) a2[j] = 0.0f;
        const float* w2h = w2 + hh * 32;
#pragma unroll 1
        for (int q = 0; q < 16; ++q) {
            const float fx = h1[4*q+0], fy = h1[4*q+1], fz = h1[4*q+2], fw = h1[4*q+3];
            const float* wr = w2h + q * 4 * DD;
#pragma unroll
            for (int j = 0; j < 32; ++j) a2[j] = fmaf(fx, wr[j], a2[j]);
#pragma unroll
            for (int j = 0; j < 32; ++j) a2[j] = fmaf(fy, wr[DD + j], a2[j]);
#pragma unroll
            for (int j = 0; j < 32; ++j) a2[j] = fmaf(fz, wr[2 * DD + j], a2[j]);
#pragma unroll
            for (int j = 0; j < 32; ++j) a2[j] = fmaf(fw, wr[3 * DD + j], a2[j]);
        }
#pragma unroll
        for (int j = 0; j < 32; ++j) {
            const int jj = hh * 32 + j;
            float sc = g2[jj] * (1.0f / sqrtf(v2[jj] + 1e-5f));
            float h  = fmaf(a2[j] + b2[jj] - m2[jj], sc, be2[jj]);
            h = fmaxf(h, 0.0f);
            a2[j] = h;
            s = fmaf(h, w3[jj], s);
        }
#pragma unroll
        for (int q = 0; q < 8; ++q)
            o[hh * 8 + q] = make_float4(a2[4*q+0], a2[4*q+1], a2[4*q+2], a2[4*q+3]);
    }
    s += b3[0];
    const float score = fmaxf(s, 0.0f);

    // sigmoid(score) > 0.5 via XLA-style logistic expansion (score >= 0)
    const bool on = (0.5f + 0.5f * tanhf(0.5f * score)) > 0.5f;

    // ---- Phase C: replay mk bits; sm/on/off stores + ballot bitmasks ----
#pragma unroll 1
    for (int p = 0; p < 64; ++p) {
        const bool mk = (mklo >> p) & 1ull;
        const size_t idx = (size_t)p * NPTS + n;
        const bool mon  = mk & on;
        const bool moff = mk & (!on);
        __builtin_nontemporal_store(mk ? score : 0.0f, &out_sm[idx]);
        __builtin_nontemporal_store(mon ? 1.0f : 0.0f, &out_on[idx]);
        __builtin_nontemporal_store(moff ? 1.0f : 0.0f, &out_off[idx]);
        unsigned long long bOn  = __ballot(mon);
        unsigned long long bOff = __ballot(moff);
        if (lane == 0) {
            hitOn [(size_t)p * NWORDS + word] = bOn;
            hitOff[(size_t)p * NWORDS + word] = bOff;
        }
    }
#pragma unroll 1
    for (int p = 64; p < 128; ++p) {
        const bool mk = (mkhi >> (p - 64)) & 1ull;
        const size_t idx = (size_t)p * NPTS + n;
        const bool mon  = mk & on;
        const bool moff = mk & (!on);
        __builtin_nontemporal_store(mk ? score : 0.0f, &out_sm[idx]);
        __builtin_nontemporal_store(mon ? 1.0f : 0.0f, &out_on[idx]);
        __builtin_nontemporal_store(moff ? 1.0f : 0.0f, &out_off[idx]);
        unsigned long long bOn  = __ballot(mon);
        unsigned long long bOff = __ballot(moff);
        if (lane == 0) {
            hitOn [(size_t)p * NWORDS + word] = bOn;
            hitOff[(size_t)p * NWORDS + word] = bOff;
        }
    }
}

// ---------------------------------------------------------------------------
// Pool: masked max of h2 per plane, register-accumulated per block, then
// atomicMax(int) into out_feats (non-negative IEEE floats compare as signed
// ints; h2 >= 0; zero-init by prep -> exact where(any,max,0) semantics).
// Wave w owns planes [32w,32w+32); lane = dim; hit loop is wave-uniform.
// tile[n*64+lane]: 2-way bank alias = free (m136).
// ---------------------------------------------------------------------------
__global__ __launch_bounds__(256) void pool_kernel(
    const float* __restrict__ h2,
    const unsigned long long* __restrict__ hitOn,
    const unsigned long long* __restrict__ hitOff,
    int* __restrict__ out_feats_i)
{
    __shared__ float tile[128 * DD];                 // 32 KB
    __shared__ unsigned long long bm[2][NP][2];      // 4 KB
    const int t = threadIdx.x;
    const int lane = t & 63;
    const int wv = t >> 6;

    float accOn[32], accOff[32];
#pragma unroll
    for (int i = 0; i < 32; ++i) { accOn[i] = 0.0f; accOff[i] = 0.0f; }

    for (int cc = 0; cc < 4; ++cc) {
        const int chunk = blockIdx.x * 4 + cc;       // 0..2047
        const int base  = chunk * 128;
        const float4* src = reinterpret_cast<const float4*>(h2 + (size_t)base * DD);
        float4* dst = reinterpret_cast<float4*>(tile);
#pragma unroll
        for (int q = 0; q < 8; ++q) dst[t + q * 256] = src[t + q * 256];
        {
            const int p = t & 127;
            const int half = t >> 7;
            const unsigned long long* hsrc = half ? hitOff : hitOn;
            const int w0 = chunk * 2;
            bm[half][p][0] = hsrc[(size_t)p * NWORDS + w0 + 0];
            bm[half][p][1] = hsrc[(size_t)p * NWORDS + w0 + 1];
        }
        __syncthreads();

#pragma unroll
        for (int i = 0; i < 32; ++i) {
            const int p = wv * 32 + i;
            unsigned long long m;
            m = bm[0][p][0];
            while (m) { int nn = __builtin_ctzll(m); m &= m - 1;
                        accOn[i]  = fmaxf(accOn[i],  tile[nn * DD + lane]); }
            m = bm[0][p][1];
            while (m) { int nn = __builtin_ctzll(m); m &= m - 1;
                        accOn[i]  = fmaxf(accOn[i],  tile[(64 + nn) * DD + lane]); }
            m = bm[1][p][0];
            while (m) { int nn = __builtin_ctzll(m); m &= m - 1;
                        accOff[i] = fmaxf(accOff[i], tile[nn * DD + lane]); }
            m = bm[1][p][1];
            while (m) { int nn = __builtin_ctzll(m); m &= m - 1;
                        accOff[i] = fmaxf(accOff[i], tile[(64 + nn) * DD + lane]); }
        }
        __syncthreads();
    }
#pragma unroll
    for (int i = 0; i < 32; ++i) {
        const int p = wv * 32 + i;
        if (accOn[i]  != 0.0f) atomicMax(&out_feats_i[p * DD + lane],            __float_as_int(accOn[i]));
        if (accOff[i] != 0.0f) atomicMax(&out_feats_i[NP * DD + p * DD + lane],  __float_as_int(accOff[i]));
    }
}

extern "C" void kernel_launch(void* const* d_in, const int* in_sizes, int n_in,
                              void* d_out, int out_size, void* d_ws, size_t ws_size,
                              hipStream_t stream) {
    const float* feature      = (const float*)d_in[0];
    const float* feature_geo  = (const float*)d_in[1];
    const float* xyz          = (const float*)d_in[2];
    const float* centers      = (const float*)d_in[3];
    const float* plane_center = (const float*)d_in[4];
    const float* plane_normal = (const float*)d_in[5];
    const float* pmin         = (const float*)d_in[6];
    const float* pmax         = (const float*)d_in[7];
    const float* w1 = (const float*)d_in[8];
    const float* b1 = (const float*)d_in[9];
    const float* g1 = (const float*)d_in[10];
    const float* be1 = (const float*)d_in[11];
    const float* m1 = (const float*)d_in[12];
    const float* v1 = (const float*)d_in[13];
    const float* w2 = (const float*)d_in[14];
    const float* b2 = (const float*)d_in[15];
    const float* g2 = (const float*)d_in[16];
    const float* be2 = (const float*)d_in[17];
    const float* m2 = (const float*)d_in[18];
    const float* v2 = (const float*)d_in[19];
    const float* w3 = (const float*)d_in[20];
    const float* b3 = (const float*)d_in[21];

    float* out = (float*)d_out;
    const size_t PN = (size_t)NP * NPTS;
    float* out_sm    = out;
    float* out_mask  = out + PN;
    float* out_on    = out + 2 * PN;
    float* out_off   = out + 3 * PN;
    float* out_feats = out + 4 * PN;

    // workspace carve (~73 MB)
    float* h2     = (float*)d_ws;                                // N*64 f32 (64 MB)
    unsigned long long* hitOn  = (unsigned long long*)(h2 + (size_t)NPTS * DD);
    unsigned long long* hitOff = hitOn + (size_t)NP * NWORDS;
    float* packed = (float*)(hitOff + (size_t)NP * NWORDS);      // P*12 f32

    prep_kernel<<<64, 256, 0, stream>>>(
        plane_center, plane_normal, pmin, pmax, packed, out_feats);
    fused_kernel<<<NPTS / 256, 256, 0, stream>>>(
        feature, feature_geo, xyz, centers, packed,
        w1, b1, g1, be1, m1, v1, w2, b2, g2, be2, m2, v2, w3, b3,
        h2, out_sm, out_mask, out_on, out_off, hitOn, hitOff);
    pool_kernel<<<512, 256, 0, stream>>>(h2, hitOn, hitOff, (int*)out_feats);
}

// Round 8
// 850.719 us; speedup vs baseline: 1.0306x; 1.0306x over previous
//
#include <hip/hip_runtime.h>
#include <hip/hip_bf16.h>
#include <math.h>

// Problem constants (fixed by the reference file)
#define NPTS 262144
#define NP   128
#define DD   64
#define NWORDS (NPTS / 64)   // 4096 u64 ballot words per plane

// Constant-address-space pointers: uniform-address loads from AS(4) lower to
// s_load_* on the SMEM pipe (guaranteed scalarization). R7 lesson: HIP's
// float4 is a class type whose ctors can't bind AS(4) references on the HOST
// pass -> use clang's builtin ext_vector (POD, no ctors) for AS(4) vectors.
#define AS4 __attribute__((address_space(4)))
typedef float evf4 __attribute__((ext_vector_type(4)));
typedef AS4 const float* csf;
typedef AS4 const evf4*  csf4;
#define TO_CSF(p)  ((csf)(unsigned long long)(const void*)(p))
#define TO_CSF4(p) ((csf4)(unsigned long long)(const void*)(p))

// ---------------------------------------------------------------------------
// Prep: pack plane params [P][12] (normal.xyz+offs | min.xyz | max.xyz),
// transpose w2 -> w2T[j][k] (so fc2's per-output rows are contiguous for
// s_load_dwordx16), zero out_feats for the atomic-max pool.
// ---------------------------------------------------------------------------
__global__ __launch_bounds__(256) void prep_kernel(
    const float* __restrict__ plane_center, const float* __restrict__ plane_normal,
    const float* __restrict__ pmin, const float* __restrict__ pmax,
    const float* __restrict__ w2,
    float* __restrict__ packed, float* __restrict__ w2T,
    float* __restrict__ out_feats)
{
    const int t = threadIdx.x;
    out_feats[blockIdx.x * 256 + t] = 0.0f;          // grid = 64 blocks
    if (blockIdx.x == 0 && t < NP) {
        float n0 = plane_normal[t*3+0], n1 = plane_normal[t*3+1], n2 = plane_normal[t*3+2];
        float c0 = plane_center[t*3+0], c1 = plane_center[t*3+1], c2 = plane_center[t*3+2];
        float off = (c0*n0 + c1*n1) + c2*n2;          // matches jnp.sum order
        float4* pp = reinterpret_cast<float4*>(packed) + t * 3;
        pp[0] = make_float4(n0, n1, n2, off);
        pp[1] = make_float4(pmin[t*3+0], pmin[t*3+1], pmin[t*3+2], 0.0f);
        pp[2] = make_float4(pmax[t*3+0], pmax[t*3+1], pmax[t*3+2], 0.0f);
    }
    if (blockIdx.x == 1) {
#pragma unroll
        for (int u = 0; u < 16; ++u) {
            const int e = u * 256 + t;               // e = j*64 + k
            const int j = e >> 6, k = e & 63;
            w2T[e] = w2[k * DD + j];
        }
    }
}

// ---------------------------------------------------------------------------
// Fused per-point kernel, round-8 (= round-7 theory, compile-fixed).
// R6 counters: VGPR=64 + ~360 MB scratch traffic = launch_bounds(256,4) made
// the allocator spill; VALU time 2x the FMA model = weight loads were per-lane
// VMEM (never scalarized); plus h1[4q+u] dynamic reg-indexing forced scratch.
// Fixes: plain launch_bounds; AS(4) casts so weight/BN/plane reads are s_load
// (SMEM pipe, SGPR operand into v_fmac); fc2 loops swapped (outer jq rolled,
// inner k=0..63 unrolled -> acc[k] static) reading prep's w2T rows.
// Phase A keeps the R6 jam: mask geometry + out_mask stores hidden under fc1
// (VMEM queue now holds only stores). Phase C replays mk bits from registers.
// Accumulation order identical to rounds 3-6 -> absmax stays 2.98e-8.
// ---------------------------------------------------------------------------
__global__ __launch_bounds__(256) void fused_kernel(
    const float* __restrict__ feature, const float* __restrict__ feature_geo,
    const float* __restrict__ xyz, const float* __restrict__ centers,
    const float* __restrict__ packed,
    const float* __restrict__ w1, const float* __restrict__ b1,
    const float* __restrict__ g1, const float* __restrict__ be1,
    const float* __restrict__ m1, const float* __restrict__ v1,
    const float* __restrict__ w2T, const float* __restrict__ b2,
    const float* __restrict__ g2, const float* __restrict__ be2,
    const float* __restrict__ m2, const float* __restrict__ v2,
    const float* __restrict__ w3, const float* __restrict__ b3,
    float* __restrict__ h2_out,
    float* __restrict__ out_sm, float* __restrict__ out_mask,
    float* __restrict__ out_on, float* __restrict__ out_off,
    unsigned long long* __restrict__ hitOn, unsigned long long* __restrict__ hitOff)
{
    const int t = threadIdx.x;
    const int n = blockIdx.x * 256 + t;
    const int lane = t & 63;
    const int word = n >> 6;

    const csf  cc  = TO_CSF(centers);
    const csf4 pp  = TO_CSF4(packed);
    const csf  w1c = TO_CSF(w1);

    // cloud coords for the jammed mask iters
    const float c0 = xyz[n*3+0] + cc[0];
    const float c1 = xyz[n*3+1] + cc[1];
    const float c2 = xyz[n*3+2] + cc[2];

    unsigned long long mklo = 0ull, mkhi = 0ull;

    float acc[DD];
#pragma unroll
    for (int j = 0; j < DD; ++j) acc[j] = 0.0f;

    // ---- Phase A part 1: fc1 x feature, jammed with planes 0..63 ----
    const float4* fA = reinterpret_cast<const float4*>(feature) + (size_t)n * 16;
    const float4* fB = reinterpret_cast<const float4*>(feature_geo) + (size_t)n * 16;
#pragma unroll 1
    for (int q = 0; q < 16; ++q) {
        const float4 fv = fA[q];
        const csf wr = w1c + q * 4 * DD;
#pragma unroll
        for (int j = 0; j < DD; ++j) acc[j] = fmaf(fv.x, wr[j], acc[j]);
#pragma unroll
        for (int j = 0; j < DD; ++j) acc[j] = fmaf(fv.y, wr[DD + j], acc[j]);
#pragma unroll
        for (int j = 0; j < DD; ++j) acc[j] = fmaf(fv.z, wr[2 * DD + j], acc[j]);
#pragma unroll
        for (int j = 0; j < DD; ++j) acc[j] = fmaf(fv.w, wr[3 * DD + j], acc[j]);
#pragma unroll
        for (int u = 0; u < 4; ++u) {
            const int p = q * 4 + u;
            const evf4 nrm = pp[p*3+0];
            const evf4 mn  = pp[p*3+1];
            const evf4 mx  = pp[p*3+2];
            float d = fabsf(fmaf(c2, nrm.z, fmaf(c1, nrm.y, c0 * nrm.x)) - nrm.w);
            bool ok0 = (mx.x == 0.0f) | ((c0 >= mn.x) & (c0 < mx.x));
            bool ok1 = (mx.y == 0.0f) | ((c1 >= mn.y) & (c1 < mx.y));
            bool ok2 = (mx.z == 0.0f) | ((c2 >= mn.z) & (c2 < mx.z));
            bool mk  = ok0 & ok1 & ok2 & (d < 0.1f);
            __builtin_nontemporal_store(mk ? 1.0f : 0.0f, &out_mask[(size_t)p * NPTS + n]);
            mklo |= ((unsigned long long)mk) << p;
        }
    }
    // ---- Phase A part 2: fc1 x feature_geo, jammed with planes 64..127 ----
    const csf w1b = w1c + DD * DD;
#pragma unroll 1
    for (int q = 0; q < 16; ++q) {
        const float4 fv = fB[q];
        const csf wr = w1b + q * 4 * DD;
#pragma unroll
        for (int j = 0; j < DD; ++j) acc[j] = fmaf(fv.x, wr[j], acc[j]);
#pragma unroll
        for (int j = 0; j < DD; ++j) acc[j] = fmaf(fv.y, wr[DD + j], acc[j]);
#pragma unroll
        for (int j = 0; j < DD; ++j) acc[j] = fmaf(fv.z, wr[2 * DD + j], acc[j]);
#pragma unroll
        for (int j = 0; j < DD; ++j) acc[j] = fmaf(fv.w, wr[3 * DD + j], acc[j]);
#pragma unroll
        for (int u = 0; u < 4; ++u) {
            const int p = 64 + q * 4 + u;
            const evf4 nrm = pp[p*3+0];
            const evf4 mn  = pp[p*3+1];
            const evf4 mx  = pp[p*3+2];
            float d = fabsf(fmaf(c2, nrm.z, fmaf(c1, nrm.y, c0 * nrm.x)) - nrm.w);
            bool ok0 = (mx.x == 0.0f) | ((c0 >= mn.x) & (c0 < mx.x));
            bool ok1 = (mx.y == 0.0f) | ((c1 >= mn.y) & (c1 < mx.y));
            bool ok2 = (mx.z == 0.0f) | ((c2 >= mn.z) & (c2 < mx.z));
            bool mk  = ok0 & ok1 & ok2 & (d < 0.1f);
            __builtin_nontemporal_store(mk ? 1.0f : 0.0f, &out_mask[(size_t)p * NPTS + n]);
            mkhi |= ((unsigned long long)mk) << (p - 64);
        }
    }
    // BN1 + ReLU in place (acc becomes h1; keeps peak regs ~85)
    {
        const csf g1c = TO_CSF(g1), v1c = TO_CSF(v1), b1c = TO_CSF(b1),
                  m1c = TO_CSF(m1), be1c = TO_CSF(be1);
#pragma unroll
        for (int j = 0; j < DD; ++j) {
            float sc = g1c[j] * (1.0f / sqrtf(v1c[j] + 1e-5f));
            float h  = fmaf(acc[j] + b1c[j] - m1c[j], sc, be1c[j]);
            acc[j] = fmaxf(h, 0.0f);
        }
    }

    // ---- Phase B: fc2 via w2T rows (jq rolled, k unrolled -> static acc[k]),
    //      BN2+ReLU+fc3 fused per 4 outputs, float4 h2 store per iter ----
    const csf w2t = TO_CSF(w2T);
    const csf g2c = TO_CSF(g2), v2c = TO_CSF(v2), b2c = TO_CSF(b2),
              m2c = TO_CSF(m2), be2c = TO_CSF(be2), w3c = TO_CSF(w3);
    float s = 0.0f;
    float4* o = reinterpret_cast<float4*>(h2_out) + (size_t)n * 16;
#pragma unroll 1
    for (int jq = 0; jq < 16; ++jq) {
        const csf r0 = w2t + (4*jq + 0) * DD;
        const csf r1 = w2t + (4*jq + 1) * DD;
        const csf r2 = w2t + (4*jq + 2) * DD;
        const csf r3 = w2t + (4*jq + 3) * DD;
        float a0 = 0.0f, a1 = 0.0f, a2 = 0.0f, a3 = 0.0f;
#pragma unroll
        for (int k = 0; k < DD; ++k) {
            const float h = acc[k];
            a0 = fmaf(h, r0[k], a0);
            a1 = fmaf(h, r1[k], a1);
            a2 = fmaf(h, r2[k], a2);
            a3 = fmaf(h, r3[k], a3);
        }
        float hv[4] = {a0, a1, a2, a3};
#pragma unroll
        for (int u = 0; u < 4; ++u) {
            const int jj = 4*jq + u;
            float sc = g2c[jj] * (1.0f / sqrtf(v2c[jj] + 1e-5f));
            float h  = fmaf(hv[u] + b2c[jj] - m2c[jj], sc, be2c[jj]);
            h = fmaxf(h, 0.0f);
            hv[u] = h;
            s = fmaf(h, w3c[jj], s);
        }
        o[jq] = make_float4(hv[0], hv[1], hv[2], hv[3]);
    }
    s += TO_CSF(b3)[0];
    const float score = fmaxf(s, 0.0f);

    // sigmoid(score) > 0.5 via XLA-style logistic expansion (score >= 0)
    const bool on = (0.5f + 0.5f * tanhf(0.5f * score)) > 0.5f;

    // ---- Phase C: replay mk bits; sm/on/off stores + ballot bitmasks ----
#pragma unroll 1
    for (int p = 0; p < 64; ++p) {
        const bool mk = (mklo >> p) & 1ull;
        const size_t idx = (size_t)p * NPTS + n;
        const bool mon  = mk & on;
        const bool moff = mk & (!on);
        __builtin_nontemporal_store(mk ? score : 0.0f, &out_sm[idx]);
        __builtin_nontemporal_store(mon ? 1.0f : 0.0f, &out_on[idx]);
        __builtin_nontemporal_store(moff ? 1.0f : 0.0f, &out_off[idx]);
        unsigned long long bOn  = __ballot(mon);
        unsigned long long bOff = __ballot(moff);
        if (lane == 0) {
            hitOn [(size_t)p * NWORDS + word] = bOn;
            hitOff[(size_t)p * NWORDS + word] = bOff;
        }
    }
#pragma unroll 1
    for (int p = 64; p < 128; ++p) {
        const bool mk = (mkhi >> (p - 64)) & 1ull;
        const size_t idx = (size_t)p * NPTS + n;
        const bool mon  = mk & on;
        const bool moff = mk & (!on);
        __builtin_nontemporal_store(mk ? score : 0.0f, &out_sm[idx]);
        __builtin_nontemporal_store(mon ? 1.0f : 0.0f, &out_on[idx]);
        __builtin_nontemporal_store(moff ? 1.0f : 0.0f, &out_off[idx]);
        unsigned long long bOn  = __ballot(mon);
        unsigned long long bOff = __ballot(moff);
        if (lane == 0) {
            hitOn [(size_t)p * NWORDS + word] = bOn;
            hitOff[(size_t)p * NWORDS + word] = bOff;
        }
    }
}

// ---------------------------------------------------------------------------
// Pool: masked max of h2 per plane, register-accumulated per block, then
// atomicMax(int) into out_feats (non-negative IEEE floats compare as signed
// ints; h2 >= 0; zero-init by prep -> exact where(any,max,0) semantics).
// Wave w owns planes [32w,32w+32); lane = dim; hit loop is wave-uniform.
// tile[n*64+lane]: 2-way bank alias = free (m136).
// ---------------------------------------------------------------------------
__global__ __launch_bounds__(256) void pool_kernel(
    const float* __restrict__ h2,
    const unsigned long long* __restrict__ hitOn,
    const unsigned long long* __restrict__ hitOff,
    int* __restrict__ out_feats_i)
{
    __shared__ float tile[128 * DD];                 // 32 KB
    __shared__ unsigned long long bm[2][NP][2];      // 4 KB
    const int t = threadIdx.x;
    const int lane = t & 63;
    const int wv = t >> 6;

    float accOn[32], accOff[32];
#pragma unroll
    for (int i = 0; i < 32; ++i) { accOn[i] = 0.0f; accOff[i] = 0.0f; }

    for (int cc = 0; cc < 4; ++cc) {
        const int chunk = blockIdx.x * 4 + cc;       // 0..2047
        const int base  = chunk * 128;
        const float4* src = reinterpret_cast<const float4*>(h2 + (size_t)base * DD);
        float4* dst = reinterpret_cast<float4*>(tile);
#pragma unroll
        for (int q = 0; q < 8; ++q) dst[t + q * 256] = src[t + q * 256];
        {
            const int p = t & 127;
            const int half = t >> 7;
            const unsigned long long* hsrc = half ? hitOff : hitOn;
            const int w0 = chunk * 2;
            bm[half][p][0] = hsrc[(size_t)p * NWORDS + w0 + 0];
            bm[half][p][1] = hsrc[(size_t)p * NWORDS + w0 + 1];
        }
        __syncthreads();

#pragma unroll
        for (int i = 0; i < 32; ++i) {
            const int p = wv * 32 + i;
            unsigned long long m;
            m = bm[0][p][0];
            while (m) { int nn = __builtin_ctzll(m); m &= m - 1;
                        accOn[i]  = fmaxf(accOn[i],  tile[nn * DD + lane]); }
            m = bm[0][p][1];
            while (m) { int nn = __builtin_ctzll(m); m &= m - 1;
                        accOn[i]  = fmaxf(accOn[i],  tile[(64 + nn) * DD + lane]); }
            m = bm[1][p][0];
            while (m) { int nn = __builtin_ctzll(m); m &= m - 1;
                        accOff[i] = fmaxf(accOff[i], tile[nn * DD + lane]); }
            m = bm[1][p][1];
            while (m) { int nn = __builtin_ctzll(m); m &= m - 1;
                        accOff[i] = fmaxf(accOff[i], tile[(64 + nn) * DD + lane]); }
        }
        __syncthreads();
    }
#pragma unroll
    for (int i = 0; i < 32; ++i) {
        const int p = wv * 32 + i;
        if (accOn[i]  != 0.0f) atomicMax(&out_feats_i[p * DD + lane],            __float_as_int(accOn[i]));
        if (accOff[i] != 0.0f) atomicMax(&out_feats_i[NP * DD + p * DD + lane],  __float_as_int(accOff[i]));
    }
}

extern "C" void kernel_launch(void* const* d_in, const int* in_sizes, int n_in,
                              void* d_out, int out_size, void* d_ws, size_t ws_size,
                              hipStream_t stream) {
    const float* feature      = (const float*)d_in[0];
    const float* feature_geo  = (const float*)d_in[1];
    const float* xyz          = (const float*)d_in[2];
    const float* centers      = (const float*)d_in[3];
    const float* plane_center = (const float*)d_in[4];
    const float* plane_normal = (const float*)d_in[5];
    const float* pmin         = (const float*)d_in[6];
    const float* pmax         = (const float*)d_in[7];
    const float* w1 = (const float*)d_in[8];
    const float* b1 = (const float*)d_in[9];
    const float* g1 = (const float*)d_in[10];
    const float* be1 = (const float*)d_in[11];
    const float* m1 = (const float*)d_in[12];
    const float* v1 = (const float*)d_in[13];
    const float* w2 = (const float*)d_in[14];
    const float* b2 = (const float*)d_in[15];
    const float* g2 = (const float*)d_in[16];
    const float* be2 = (const float*)d_in[17];
    const float* m2 = (const float*)d_in[18];
    const float* v2 = (const float*)d_in[19];
    const float* w3 = (const float*)d_in[20];
    const float* b3 = (const float*)d_in[21];

    float* out = (float*)d_out;
    const size_t PN = (size_t)NP * NPTS;
    float* out_sm    = out;
    float* out_mask  = out + PN;
    float* out_on    = out + 2 * PN;
    float* out_off   = out + 3 * PN;
    float* out_feats = out + 4 * PN;

    // workspace carve (~73 MB)
    float* h2     = (float*)d_ws;                                // N*64 f32 (64 MB)
    unsigned long long* hitOn  = (unsigned long long*)(h2 + (size_t)NPTS * DD);
    unsigned long long* hitOff = hitOn + (size_t)NP * NWORDS;
    float* packed = (float*)(hitOff + (size_t)NP * NWORDS);      // P*12 f32
    float* w2T    = packed + NP * 12;                            // 64*64 f32

    prep_kernel<<<64, 256, 0, stream>>>(
        plane_center, plane_normal, pmin, pmax, w2, packed, w2T, out_feats);
    fused_kernel<<<NPTS / 256, 256, 0, stream>>>(
        feature, feature_geo, xyz, centers, packed,
        w1, b1, g1, be1, m1, v1, w2T, b2, g2, be2, m2, v2, w3, b3,
        h2, out_sm, out_mask, out_on, out_off, hitOn, hitOff);
    pool_kernel<<<512, 256, 0, stream>>>(h2, hitOn, hitOff, (int*)out_feats);
}

// Round 9
// 835.784 us; speedup vs baseline: 1.0490x; 1.0179x over previous
//
#include <hip/hip_runtime.h>
#include <hip/hip_bf16.h>
#include <math.h>

// Problem constants (fixed by the reference file)
#define NPTS 262144
#define NP   128
#define DD   64
#define NWORDS (NPTS / 64)   // 4096 u64 ballot words per plane

// AS(4) scalar pointers for small uniform reads (planes/BN). R7 lesson: use
// POD ext_vector for AS(4) vectors (HIP float4 ctors break the host pass).
#define AS4 __attribute__((address_space(4)))
typedef float evf4 __attribute__((ext_vector_type(4)));
typedef AS4 const float* csf;
typedef AS4 const evf4*  csf4;
#define TO_CSF(p)  ((csf)(unsigned long long)(const void*)(p))
#define TO_CSF4(p) ((csf4)(unsigned long long)(const void*)(p))

// ---------------------------------------------------------------------------
// Prep: pack plane params [P][12] (normal.xyz+offs | min.xyz | max.xyz),
// transpose w2 -> w2T[j][k], zero out_feats for the atomic-max pool.
// ---------------------------------------------------------------------------
__global__ __launch_bounds__(256) void prep_kernel(
    const float* __restrict__ plane_center, const float* __restrict__ plane_normal,
    const float* __restrict__ pmin, const float* __restrict__ pmax,
    const float* __restrict__ w2,
    float* __restrict__ packed, float* __restrict__ w2T,
    float* __restrict__ out_feats)
{
    const int t = threadIdx.x;
    out_feats[blockIdx.x * 256 + t] = 0.0f;          // grid = 64 blocks
    if (blockIdx.x == 0 && t < NP) {
        float n0 = plane_normal[t*3+0], n1 = plane_normal[t*3+1], n2 = plane_normal[t*3+2];
        float c0 = plane_center[t*3+0], c1 = plane_center[t*3+1], c2 = plane_center[t*3+2];
        float off = (c0*n0 + c1*n1) + c2*n2;          // matches jnp.sum order
        float4* pp = reinterpret_cast<float4*>(packed) + t * 3;
        pp[0] = make_float4(n0, n1, n2, off);
        pp[1] = make_float4(pmin[t*3+0], pmin[t*3+1], pmin[t*3+2], 0.0f);
        pp[2] = make_float4(pmax[t*3+0], pmax[t*3+1], pmax[t*3+2], 0.0f);
    }
    if (blockIdx.x == 1) {
#pragma unroll
        for (int u = 0; u < 16; ++u) {
            const int e = u * 256 + t;               // e = j*64 + k
            const int j = e >> 6, k = e & 63;
            w2T[e] = w2[k * DD + j];
        }
    }
}

// ---------------------------------------------------------------------------
// Fused per-point kernel, round-9: LDS-staged weights.
// R2-R8 evidence: fc phase stuck at ~5-6x its 41us FMA floor in every
// structure; theory = scalar weight loads chop the FMA stream with lgkmcnt
// waits (SGPR file can't hold a q-iteration's 256 weights). Fix: stage
// w1 (32KB) + w2T (16KB) in LDS once per block (48KB -> 3 blocks/CU), read
// wave-uniform ds_read_b128 broadcasts (conflict-free; ~12K LDS-cyc vs
// ~24.7K VALU-cyc per wave -> hidden). De-jammed: Phase A/B pure fc,
// Phase C all geometry + 4 output stores + ballots (plane params via AS(4)
// s_load there; no ds/s_load mixing inside FMA loops). Dropped nontemporal
// (R5: slightly negative). FMA order bit-identical -> absmax 2.98e-8.
// ---------------------------------------------------------------------------
__global__ __launch_bounds__(256) void fused_kernel(
    const float* __restrict__ feature, const float* __restrict__ feature_geo,
    const float* __restrict__ xyz, const float* __restrict__ centers,
    const float* __restrict__ packed,
    const float* __restrict__ w1, const float* __restrict__ b1,
    const float* __restrict__ g1, const float* __restrict__ be1,
    const float* __restrict__ m1, const float* __restrict__ v1,
    const float* __restrict__ w2T, const float* __restrict__ b2,
    const float* __restrict__ g2, const float* __restrict__ be2,
    const float* __restrict__ m2, const float* __restrict__ v2,
    const float* __restrict__ w3, const float* __restrict__ b3,
    float* __restrict__ h2_out,
    float* __restrict__ out_sm, float* __restrict__ out_mask,
    float* __restrict__ out_on, float* __restrict__ out_off,
    unsigned long long* __restrict__ hitOn, unsigned long long* __restrict__ hitOff)
{
    __shared__ float sw1[128 * DD];   // 32 KB, row-major [k][j] like w1
    __shared__ float sw2[DD * DD];    // 16 KB, w2T layout [j][k]
    const int t = threadIdx.x;
    const int n = blockIdx.x * 256 + t;
    const int lane = t & 63;
    const int word = n >> 6;

    // stage weights (coalesced float4; 12 per thread)
    {
        const float4* s1 = reinterpret_cast<const float4*>(w1);
        const float4* s2 = reinterpret_cast<const float4*>(w2T);
        float4* d1 = reinterpret_cast<float4*>(sw1);
        float4* d2 = reinterpret_cast<float4*>(sw2);
#pragma unroll
        for (int k = 0; k < 8; ++k) d1[t + k * 256] = s1[t + k * 256];
#pragma unroll
        for (int k = 0; k < 4; ++k) d2[t + k * 256] = s2[t + k * 256];
    }

    // cloud coords (issue early; used in Phase C)
    const csf cc = TO_CSF(centers);
    const float c0 = xyz[n*3+0] + cc[0];
    const float c1 = xyz[n*3+1] + cc[1];
    const float c2 = xyz[n*3+2] + cc[2];

    __syncthreads();

    float acc[DD];
#pragma unroll
    for (int j = 0; j < DD; ++j) acc[j] = 0.0f;

    // ---- Phase A: fc1 from LDS (q rolled, j-blocks as 16x b128) ----
    const float4* fA = reinterpret_cast<const float4*>(feature) + (size_t)n * 16;
    const float4* fB = reinterpret_cast<const float4*>(feature_geo) + (size_t)n * 16;
#pragma unroll 1
    for (int q = 0; q < 16; ++q) {
        const float4 fv = fA[q];
        const evf4* wr = reinterpret_cast<const evf4*>(sw1 + q * 4 * DD);
#pragma unroll
        for (int j4 = 0; j4 < 16; ++j4) { const evf4 w = wr[j4];
            acc[4*j4+0] = fmaf(fv.x, w.x, acc[4*j4+0]);
            acc[4*j4+1] = fmaf(fv.x, w.y, acc[4*j4+1]);
            acc[4*j4+2] = fmaf(fv.x, w.z, acc[4*j4+2]);
            acc[4*j4+3] = fmaf(fv.x, w.w, acc[4*j4+3]); }
#pragma unroll
        for (int j4 = 0; j4 < 16; ++j4) { const evf4 w = wr[16 + j4];
            acc[4*j4+0] = fmaf(fv.y, w.x, acc[4*j4+0]);
            acc[4*j4+1] = fmaf(fv.y, w.y, acc[4*j4+1]);
            acc[4*j4+2] = fmaf(fv.y, w.z, acc[4*j4+2]);
            acc[4*j4+3] = fmaf(fv.y, w.w, acc[4*j4+3]); }
#pragma unroll
        for (int j4 = 0; j4 < 16; ++j4) { const evf4 w = wr[32 + j4];
            acc[4*j4+0] = fmaf(fv.z, w.x, acc[4*j4+0]);
            acc[4*j4+1] = fmaf(fv.z, w.y, acc[4*j4+1]);
            acc[4*j4+2] = fmaf(fv.z, w.z, acc[4*j4+2]);
            acc[4*j4+3] = fmaf(fv.z, w.w, acc[4*j4+3]); }
#pragma unroll
        for (int j4 = 0; j4 < 16; ++j4) { const evf4 w = wr[48 + j4];
            acc[4*j4+0] = fmaf(fv.w, w.x, acc[4*j4+0]);
            acc[4*j4+1] = fmaf(fv.w, w.y, acc[4*j4+1]);
            acc[4*j4+2] = fmaf(fv.w, w.z, acc[4*j4+2]);
            acc[4*j4+3] = fmaf(fv.w, w.w, acc[4*j4+3]); }
    }
#pragma unroll 1
    for (int q = 0; q < 16; ++q) {
        const float4 fv = fB[q];
        const evf4* wr = reinterpret_cast<const evf4*>(sw1 + (DD + q * 4) * DD);
#pragma unroll
        for (int j4 = 0; j4 < 16; ++j4) { const evf4 w = wr[j4];
            acc[4*j4+0] = fmaf(fv.x, w.x, acc[4*j4+0]);
            acc[4*j4+1] = fmaf(fv.x, w.y, acc[4*j4+1]);
            acc[4*j4+2] = fmaf(fv.x, w.z, acc[4*j4+2]);
            acc[4*j4+3] = fmaf(fv.x, w.w, acc[4*j4+3]); }
#pragma unroll
        for (int j4 = 0; j4 < 16; ++j4) { const evf4 w = wr[16 + j4];
            acc[4*j4+0] = fmaf(fv.y, w.x, acc[4*j4+0]);
            acc[4*j4+1] = fmaf(fv.y, w.y, acc[4*j4+1]);
            acc[4*j4+2] = fmaf(fv.y, w.z, acc[4*j4+2]);
            acc[4*j4+3] = fmaf(fv.y, w.w, acc[4*j4+3]); }
#pragma unroll
        for (int j4 = 0; j4 < 16; ++j4) { const evf4 w = wr[32 + j4];
            acc[4*j4+0] = fmaf(fv.z, w.x, acc[4*j4+0]);
            acc[4*j4+1] = fmaf(fv.z, w.y, acc[4*j4+1]);
            acc[4*j4+2] = fmaf(fv.z, w.z, acc[4*j4+2]);
            acc[4*j4+3] = fmaf(fv.z, w.w, acc[4*j4+3]); }
#pragma unroll
        for (int j4 = 0; j4 < 16; ++j4) { const evf4 w = wr[48 + j4];
            acc[4*j4+0] = fmaf(fv.w, w.x, acc[4*j4+0]);
            acc[4*j4+1] = fmaf(fv.w, w.y, acc[4*j4+1]);
            acc[4*j4+2] = fmaf(fv.w, w.z, acc[4*j4+2]);
            acc[4*j4+3] = fmaf(fv.w, w.w, acc[4*j4+3]); }
    }
    // BN1 + ReLU in place (exact same arithmetic/order as R3-R8)
    {
        const csf g1c = TO_CSF(g1), v1c = TO_CSF(v1), b1c = TO_CSF(b1),
                  m1c = TO_CSF(m1), be1c = TO_CSF(be1);
#pragma unroll
        for (int j = 0; j < DD; ++j) {
            float sc = g1c[j] * (1.0f / sqrtf(v1c[j] + 1e-5f));
            float h  = fmaf(acc[j] + b1c[j] - m1c[j], sc, be1c[j]);
            acc[j] = fmaxf(h, 0.0f);
        }
    }

    // ---- Phase B: fc2 from LDS w2T rows + BN2 + ReLU + fc3 + h2 store ----
    const csf g2c = TO_CSF(g2), v2c = TO_CSF(v2), b2c = TO_CSF(b2),
              m2c = TO_CSF(m2), be2c = TO_CSF(be2), w3c = TO_CSF(w3);
    float s = 0.0f;
    float4* o = reinterpret_cast<float4*>(h2_out) + (size_t)n * 16;
#pragma unroll 1
    for (int jq = 0; jq < 16; ++jq) {
        const evf4* r0 = reinterpret_cast<const evf4*>(sw2 + (4*jq + 0) * DD);
        const evf4* r1 = reinterpret_cast<const evf4*>(sw2 + (4*jq + 1) * DD);
        const evf4* r2 = reinterpret_cast<const evf4*>(sw2 + (4*jq + 2) * DD);
        const evf4* r3 = reinterpret_cast<const evf4*>(sw2 + (4*jq + 3) * DD);
        float a0 = 0.0f, a1 = 0.0f, a2 = 0.0f, a3 = 0.0f;
#pragma unroll
        for (int k4 = 0; k4 < 16; ++k4) {
            const evf4 w0 = r0[k4], w1v = r1[k4], w2v = r2[k4], w3v = r3[k4];
            const float h0 = acc[4*k4+0], h1v = acc[4*k4+1],
                        h2v = acc[4*k4+2], h3v = acc[4*k4+3];
            a0 = fmaf(h0, w0.x, a0); a0 = fmaf(h1v, w0.y, a0);
            a0 = fmaf(h2v, w0.z, a0); a0 = fmaf(h3v, w0.w, a0);
            a1 = fmaf(h0, w1v.x, a1); a1 = fmaf(h1v, w1v.y, a1);
            a1 = fmaf(h2v, w1v.z, a1); a1 = fmaf(h3v, w1v.w, a1);
            a2 = fmaf(h0, w2v.x, a2); a2 = fmaf(h1v, w2v.y, a2);
            a2 = fmaf(h2v, w2v.z, a2); a2 = fmaf(h3v, w2v.w, a2);
            a3 = fmaf(h0, w3v.x, a3); a3 = fmaf(h1v, w3v.y, a3);
            a3 = fmaf(h2v, w3v.z, a3); a3 = fmaf(h3v, w3v.w, a3);
        }
        float hv[4] = {a0, a1, a2, a3};
#pragma unroll
        for (int u = 0; u < 4; ++u) {
            const int jj = 4*jq + u;
            float sc = g2c[jj] * (1.0f / sqrtf(v2c[jj] + 1e-5f));
            float h  = fmaf(hv[u] + b2c[jj] - m2c[jj], sc, be2c[jj]);
            h = fmaxf(h, 0.0f);
            hv[u] = h;
            s = fmaf(h, w3c[jj], s);
        }
        o[jq] = make_float4(hv[0], hv[1], hv[2], hv[3]);
    }
    s += TO_CSF(b3)[0];
    const float score = fmaxf(s, 0.0f);

    // sigmoid(score) > 0.5 via XLA-style logistic expansion (score >= 0)
    const bool on = (0.5f + 0.5f * tanhf(0.5f * score)) > 0.5f;

    // ---- Phase C: geometry + 4 output stores + ballots per plane ----
    const csf4 pp = TO_CSF4(packed);
#pragma unroll 1
    for (int p = 0; p < NP; ++p) {
        const evf4 nrm = pp[p*3+0];
        const evf4 mn  = pp[p*3+1];
        const evf4 mx  = pp[p*3+2];
        float d = fabsf(fmaf(c2, nrm.z, fmaf(c1, nrm.y, c0 * nrm.x)) - nrm.w);
        bool ok0 = (mx.x == 0.0f) | ((c0 >= mn.x) & (c0 < mx.x));
        bool ok1 = (mx.y == 0.0f) | ((c1 >= mn.y) & (c1 < mx.y));
        bool ok2 = (mx.z == 0.0f) | ((c2 >= mn.z) & (c2 < mx.z));
        bool mk  = ok0 & ok1 & ok2 & (d < 0.1f);
        const size_t idx = (size_t)p * NPTS + n;
        const bool mon  = mk & on;
        const bool moff = mk & (!on);
        out_mask[idx] = mk ? 1.0f : 0.0f;
        out_sm[idx]   = mk ? score : 0.0f;
        out_on[idx]   = mon ? 1.0f : 0.0f;
        out_off[idx]  = moff ? 1.0f : 0.0f;
        unsigned long long bOn  = __ballot(mon);
        unsigned long long bOff = __ballot(moff);
        if (lane == 0) {
            hitOn [(size_t)p * NWORDS + word] = bOn;
            hitOff[(size_t)p * NWORDS + word] = bOff;
        }
    }
}

// ---------------------------------------------------------------------------
// Pool: masked max of h2 per plane, register-accumulated per block, then
// atomicMax(int) into out_feats (non-negative IEEE floats compare as signed
// ints; h2 >= 0; zero-init by prep -> exact where(any,max,0) semantics).
// Wave w owns planes [32w,32w+32); lane = dim; hit loop is wave-uniform.
// tile[n*64+lane]: 2-way bank alias = free (m136).
// ---------------------------------------------------------------------------
__global__ __launch_bounds__(256) void pool_kernel(
    const float* __restrict__ h2,
    const unsigned long long* __restrict__ hitOn,
    const unsigned long long* __restrict__ hitOff,
    int* __restrict__ out_feats_i)
{
    __shared__ float tile[128 * DD];                 // 32 KB
    __shared__ unsigned long long bm[2][NP][2];      // 4 KB
    const int t = threadIdx.x;
    const int lane = t & 63;
    const int wv = t >> 6;

    float accOn[32], accOff[32];
#pragma unroll
    for (int i = 0; i < 32; ++i) { accOn[i] = 0.0f; accOff[i] = 0.0f; }

    for (int cc = 0; cc < 4; ++cc) {
        const int chunk = blockIdx.x * 4 + cc;       // 0..2047
        const int base  = chunk * 128;
        const float4* src = reinterpret_cast<const float4*>(h2 + (size_t)base * DD);
        float4* dst = reinterpret_cast<float4*>(tile);
#pragma unroll
        for (int q = 0; q < 8; ++q) dst[t + q * 256] = src[t + q * 256];
        {
            const int p = t & 127;
            const int half = t >> 7;
            const unsigned long long* hsrc = half ? hitOff : hitOn;
            const int w0 = chunk * 2;
            bm[half][p][0] = hsrc[(size_t)p * NWORDS + w0 + 0];
            bm[half][p][1] = hsrc[(size_t)p * NWORDS + w0 + 1];
        }
        __syncthreads();

#pragma unroll
        for (int i = 0; i < 32; ++i) {
            const int p = wv * 32 + i;
            unsigned long long m;
            m = bm[0][p][0];
            while (m) { int nn = __builtin_ctzll(m); m &= m - 1;
                        accOn[i]  = fmaxf(accOn[i],  tile[nn * DD + lane]); }
            m = bm[0][p][1];
            while (m) { int nn = __builtin_ctzll(m); m &= m - 1;
                        accOn[i]  = fmaxf(accOn[i],  tile[(64 + nn) * DD + lane]); }
            m = bm[1][p][0];
            while (m) { int nn = __builtin_ctzll(m); m &= m - 1;
                        accOff[i] = fmaxf(accOff[i], tile[nn * DD + lane]); }
            m = bm[1][p][1];
            while (m) { int nn = __builtin_ctzll(m); m &= m - 1;
                        accOff[i] = fmaxf(accOff[i], tile[(64 + nn) * DD + lane]); }
        }
        __syncthreads();
    }
#pragma unroll
    for (int i = 0; i < 32; ++i) {
        const int p = wv * 32 + i;
        if (accOn[i]  != 0.0f) atomicMax(&out_feats_i[p * DD + lane],            __float_as_int(accOn[i]));
        if (accOff[i] != 0.0f) atomicMax(&out_feats_i[NP * DD + p * DD + lane],  __float_as_int(accOff[i]));
    }
}

extern "C" void kernel_launch(void* const* d_in, const int* in_sizes, int n_in,
                              void* d_out, int out_size, void* d_ws, size_t ws_size,
                              hipStream_t stream) {
    const float* feature      = (const float*)d_in[0];
    const float* feature_geo  = (const float*)d_in[1];
    const float* xyz          = (const float*)d_in[2];
    const float* centers      = (const float*)d_in[3];
    const float* plane_center = (const float*)d_in[4];
    const float* plane_normal = (const float*)d_in[5];
    const float* pmin         = (const float*)d_in[6];
    const float* pmax         = (const float*)d_in[7];
    const float* w1 = (const float*)d_in[8];
    const float* b1 = (const float*)d_in[9];
    const float* g1 = (const float*)d_in[10];
    const float* be1 = (const float*)d_in[11];
    const float* m1 = (const float*)d_in[12];
    const float* v1 = (const float*)d_in[13];
    const float* w2 = (const float*)d_in[14];
    const float* b2 = (const float*)d_in[15];
    const float* g2 = (const float*)d_in[16];
    const float* be2 = (const float*)d_in[17];
    const float* m2 = (const float*)d_in[18];
    const float* v2 = (const float*)d_in[19];
    const float* w3 = (const float*)d_in[20];
    const float* b3 = (const float*)d_in[21];

    float* out = (float*)d_out;
    const size_t PN = (size_t)NP * NPTS;
    float* out_sm    = out;
    float* out_mask  = out + PN;
    float* out_on    = out + 2 * PN;
    float* out_off   = out + 3 * PN;
    float* out_feats = out + 4 * PN;

    // workspace carve (~73 MB)
    float* h2     = (float*)d_ws;                                // N*64 f32 (64 MB)
    unsigned long long* hitOn  = (unsigned long long*)(h2 + (size_t)NPTS * DD);
    unsigned long long* hitOff = hitOn + (size_t)NP * NWORDS;
    float* packed = (float*)(hitOff + (size_t)NP * NWORDS);      // P*12 f32
    float* w2T    = packed + NP * 12;                            // 64*64 f32

    prep_kernel<<<64, 256, 0, stream>>>(
        plane_center, plane_normal, pmin, pmax, w2, packed, w2T, out_feats);
    fused_kernel<<<NPTS / 256, 256, 0, stream>>>(
        feature, feature_geo, xyz, centers, packed,
        w1, b1, g1, be1, m1, v1, w2T, b2, g2, be2, m2, v2, w3, b3,
        h2, out_sm, out_mask, out_on, out_off, hitOn, hitOff);
    pool_kernel<<<512, 256, 0, stream>>>(h2, hitOn, hitOff, (int*)out_feats);
}